// Round 1
// baseline (525.116 us; speedup 1.0000x reference)
//
#include <hip/hip_runtime.h>

#define HW 512
#define G 64

// Tap tables for jax.image.resize(bilinear, antialias=True) downsample.
// scale x2 (128 -> 64): sample_f = 2o+0.5, triangle kernel scaled by 2.
__device__ __forceinline__ int taps_s2(int o, int* idx, float* w) {
    if (o == 0) {
        idx[0] = 0; idx[1] = 1; idx[2] = 2;
        w[0] = 3.0f / 7.0f; w[1] = 3.0f / 7.0f; w[2] = 1.0f / 7.0f;
        return 3;
    } else if (o == 63) {
        idx[0] = 125; idx[1] = 126; idx[2] = 127;
        w[0] = 1.0f / 7.0f; w[1] = 3.0f / 7.0f; w[2] = 3.0f / 7.0f;
        return 3;
    } else {
        int base = 2 * o - 1;
        idx[0] = base; idx[1] = base + 1; idx[2] = base + 2; idx[3] = base + 3;
        w[0] = 0.125f; w[1] = 0.375f; w[2] = 0.375f; w[3] = 0.125f;
        return 4;
    }
}

// scale x4 (256 -> 64): sample_f = 4o+1.5, triangle kernel scaled by 4.
__device__ __forceinline__ int taps_s4(int o, int* idx, float* w) {
    if (o == 0) {
        const float inv = 1.0f / 28.0f;
        const float ww[6] = {5.f, 7.f, 7.f, 5.f, 3.f, 1.f};
        #pragma unroll
        for (int i = 0; i < 6; i++) { idx[i] = i; w[i] = ww[i] * inv; }
        return 6;
    } else if (o == 63) {
        const float inv = 1.0f / 28.0f;
        const float ww[6] = {1.f, 3.f, 5.f, 7.f, 7.f, 5.f};
        #pragma unroll
        for (int i = 0; i < 6; i++) { idx[i] = 250 + i; w[i] = ww[i] * inv; }
        return 6;
    } else {
        const float inv = 1.0f / 32.0f;
        const float ww[8] = {1.f, 3.f, 5.f, 7.f, 7.f, 5.f, 3.f, 1.f};
        int base = 4 * o - 2;
        #pragma unroll
        for (int i = 0; i < 8; i++) { idx[i] = base + i; w[i] = ww[i] * inv; }
        return 8;
    }
}

// grid: x = 16 (groups of 4 output rows), y = 9 (s*3+c), z = 64 (b)
// block: (64, 4) -> threadIdx.x = ox (coalesced), threadIdx.y = oy sub-row
__global__ __launch_bounds__(256) void glimpse_kernel(
    const float* __restrict__ img0,
    const float* __restrict__ img2,
    const float* __restrict__ img4,
    const float* __restrict__ loc,
    float* __restrict__ out)
{
    const int ox = threadIdx.x;
    const int oy = blockIdx.x * 4 + threadIdx.y;
    const int sc = blockIdx.y;   // s*3 + c
    const int b  = blockIdx.z;
    const int s  = sc / 3;
    const int c  = sc % 3;

    // start index, must match: (0.5*((loc+1)*(512-1))).astype(int32)
    const float lx = loc[b * 2 + 0];
    const float ly = loc[b * 2 + 1];
    const int stx = (int)(0.5f * ((lx + 1.0f) * 511.0f));
    const int sty = (int)(0.5f * ((ly + 1.0f) * 511.0f));

    float val = 0.0f;

    if (s == 0) {
        const float* img = img0 + ((size_t)b * 3 + c) * HW * HW;
        const int iy = sty + oy - 32;
        const int ix = stx + ox - 32;
        if (iy >= 0 && iy < HW && ix >= 0 && ix < HW)
            val = img[iy * HW + ix];
    } else if (s == 1) {
        const float* img = img2 + ((size_t)b * 3 + c) * HW * HW;
        int xi[4], yi[4];
        float xw[4], yw[4];
        const int ntx = taps_s2(ox, xi, xw);
        const int nty = taps_s2(oy, yi, yw);
        // patch coord i -> image coord st + i - 64 (pad = 64)
        for (int ty = 0; ty < nty; ty++) {
            const int row = sty + yi[ty] - 64;
            if (row < 0 || row >= HW) continue;
            const float* rp = img + row * HW;
            float xsum = 0.0f;
            for (int tx = 0; tx < ntx; tx++) {
                const int col = stx + xi[tx] - 64;
                if (col >= 0 && col < HW) xsum += xw[tx] * rp[col];
            }
            val += yw[ty] * xsum;
        }
    } else {
        const float* img = img4 + ((size_t)b * 3 + c) * HW * HW;
        int xi[8], yi[8];
        float xw[8], yw[8];
        const int ntx = taps_s4(ox, xi, xw);
        const int nty = taps_s4(oy, yi, yw);
        // patch coord i -> image coord st + i - 128 (pad = 128)
        for (int ty = 0; ty < nty; ty++) {
            const int row = sty + yi[ty] - 128;
            if (row < 0 || row >= HW) continue;
            const float* rp = img + row * HW;
            float xsum = 0.0f;
            for (int tx = 0; tx < ntx; tx++) {
                const int col = stx + xi[tx] - 128;
                if (col >= 0 && col < HW) xsum += xw[tx] * rp[col];
            }
            val += yw[ty] * xsum;
        }
    }

    // out[b, s, c, oy, ox]
    out[((((size_t)b * 3 + s) * 3 + c) * G + oy) * G + ox] = val;
}

extern "C" void kernel_launch(void* const* d_in, const int* in_sizes, int n_in,
                              void* d_out, int out_size, void* d_ws, size_t ws_size,
                              hipStream_t stream) {
    const float* img0 = (const float*)d_in[0];
    const float* img2 = (const float*)d_in[1];
    const float* img4 = (const float*)d_in[2];
    const float* loc  = (const float*)d_in[3];
    float* out = (float*)d_out;

    dim3 block(64, 4, 1);
    dim3 grid(16, 9, 64);
    glimpse_kernel<<<grid, block, 0, stream>>>(img0, img2, img4, loc, out);
}

// Round 2
// 481.922 us; speedup vs baseline: 1.0896x; 1.0896x over previous
//
#include <hip/hip_runtime.h>

#define HW 512
#define G 64

// Uniform tap tables (fixed count, zero weights at edges) for
// jax.image.resize(bilinear, antialias=True) downsample.
// scale x2 (128 -> 64): center = 2o+0.5, taps 2o-1..2o+2, w [1,3,3,1]/8.
__device__ __forceinline__ void taps_s2(int o, int* idx, float* w) {
    if (o == 0) {
        idx[0] = 0; idx[1] = 0; idx[2] = 1; idx[3] = 2;
        w[0] = 0.0f; w[1] = 3.0f / 7.0f; w[2] = 3.0f / 7.0f; w[3] = 1.0f / 7.0f;
    } else if (o == 63) {
        idx[0] = 125; idx[1] = 126; idx[2] = 127; idx[3] = 127;
        w[0] = 1.0f / 7.0f; w[1] = 3.0f / 7.0f; w[2] = 3.0f / 7.0f; w[3] = 0.0f;
    } else {
        int base = 2 * o - 1;
        idx[0] = base; idx[1] = base + 1; idx[2] = base + 2; idx[3] = base + 3;
        w[0] = 0.125f; w[1] = 0.375f; w[2] = 0.375f; w[3] = 0.125f;
    }
}

// scale x4 (256 -> 64): center = 4o+1.5, taps 4o-2..4o+5, w [1,3,5,7,7,5,3,1]/32.
__device__ __forceinline__ void taps_s4(int o, int* idx, float* w) {
    if (o == 0) {
        const float inv = 1.0f / 28.0f;
        const float ww[8] = {0.f, 0.f, 5.f, 7.f, 7.f, 5.f, 3.f, 1.f};
        const int  ii[8] = {0, 0, 0, 1, 2, 3, 4, 5};
        #pragma unroll
        for (int i = 0; i < 8; i++) { idx[i] = ii[i]; w[i] = ww[i] * inv; }
    } else if (o == 63) {
        const float inv = 1.0f / 28.0f;
        const float ww[8] = {1.f, 3.f, 5.f, 7.f, 7.f, 5.f, 0.f, 0.f};
        const int  ii[8] = {250, 251, 252, 253, 254, 255, 255, 255};
        #pragma unroll
        for (int i = 0; i < 8; i++) { idx[i] = ii[i]; w[i] = ww[i] * inv; }
    } else {
        const float inv = 1.0f / 32.0f;
        const float ww[8] = {1.f, 3.f, 5.f, 7.f, 7.f, 5.f, 3.f, 1.f};
        int base = 4 * o - 2;
        #pragma unroll
        for (int i = 0; i < 8; i++) { idx[i] = base + i; w[i] = ww[i] * inv; }
    }
}

// 1D grid, 768 blocks x 256 threads.
// blocks [0,384): s=2 (x4 scale), 2 blocks per (b,c) tile (oy halves) -- heaviest first
// blocks [384,576): s=1 (x2 scale), 1 block per (b,c)
// blocks [576,768): s=0 (copy),     1 block per (b,c)
__global__ __launch_bounds__(256) void glimpse_kernel(
    const float* __restrict__ img0,
    const float* __restrict__ img2,
    const float* __restrict__ img4,
    const float* __restrict__ loc,
    float* __restrict__ out)
{
    __shared__ float v[8192];  // 32 KB: s1 -> v[64][128], s2 -> v[32][256]

    const int t = threadIdx.x;
    const int blk = blockIdx.x;
    int s, bc, half = 0;
    if (blk < 384)      { s = 2; bc = blk >> 1; half = blk & 1; }
    else if (blk < 576) { s = 1; bc = blk - 384; }
    else                { s = 0; bc = blk - 576; }
    const int b = bc / 3;  // bc = b*3 + c; plane index into [B,3,H,W] is exactly bc

    const float lx = loc[2 * b];
    const float ly = loc[2 * b + 1];
    const int stx = (int)(0.5f * ((lx + 1.0f) * 511.0f));
    const int sty = (int)(0.5f * ((ly + 1.0f) * 511.0f));

    float* outp = out + (((size_t)(b * 3 + s) * 3 + (bc - b * 3)) * G) * G;

    if (s == 0) {
        const float* img = img0 + (size_t)bc * HW * HW;
        #pragma unroll
        for (int i = 0; i < 16; i++) {
            int n = i * 256 + t;
            int oy = n >> 6, ox = n & 63;
            int gy = sty + oy - 32, gx = stx + ox - 32;
            float val = 0.0f;
            if (gy >= 0 && gy < HW && gx >= 0 && gx < HW)
                val = img[gy * HW + gx];
            outp[n] = val;
        }
        return;
    }

    if (s == 1) {
        const float* img = img2 + (size_t)bc * HW * HW;
        // Pass 1: vertical filter, global (coalesced) -> LDS v[oy][col], col in [0,128)
        const int col = t & 127;          // lanes -> consecutive cols
        const int gx = stx - 64 + col;
        const bool xok = (gx >= 0 && gx < HW);
        #pragma unroll 4
        for (int i = 0; i < 32; i++) {
            int n = i * 256 + t;
            int oy = n >> 7;
            float acc = 0.0f;
            if (xok) {
                int ri[4]; float rw[4];
                taps_s2(oy, ri, rw);
                #pragma unroll
                for (int k = 0; k < 4; k++) {
                    int gy = sty - 64 + ri[k];
                    if (gy >= 0 && gy < HW) acc += rw[k] * img[gy * HW + gx];
                }
            }
            v[n] = acc;
        }
        __syncthreads();
        // Pass 2: horizontal filter from LDS, coalesced store
        #pragma unroll 4
        for (int i = 0; i < 16; i++) {
            int m = i * 256 + t;
            int ox = m & 63, oy = m >> 6;
            int xi[4]; float xw[4];
            taps_s2(ox, xi, xw);
            float acc = 0.0f;
            #pragma unroll
            for (int k = 0; k < 4; k++) acc += xw[k] * v[oy * 128 + xi[k]];
            outp[m] = acc;
        }
        return;
    }

    // s == 2
    const float* img = img4 + (size_t)bc * HW * HW;
    const int oy0 = half * 32;
    // Pass 1: vertical filter, global (coalesced) -> LDS v[oyl][col], col in [0,256)
    {
        const int col = t;                 // 256 threads = 256 cols, col fixed per thread
        const int gx = stx - 128 + col;
        const bool xok = (gx >= 0 && gx < HW);
        #pragma unroll 4
        for (int i = 0; i < 32; i++) {     // oyl = i
            int oy = oy0 + i;
            float acc = 0.0f;
            if (xok) {
                int ri[8]; float rw[8];
                taps_s4(oy, ri, rw);
                #pragma unroll
                for (int k = 0; k < 8; k++) {
                    int gy = sty - 128 + ri[k];
                    if (gy >= 0 && gy < HW) acc += rw[k] * img[gy * HW + gx];
                }
            }
            v[i * 256 + col] = acc;
        }
    }
    __syncthreads();
    // Pass 2: horizontal 8-tap from LDS, coalesced store
    #pragma unroll 4
    for (int i = 0; i < 8; i++) {
        int m = i * 256 + t;
        int ox = m & 63, oyl = m >> 6;     // oyl in [0,32)
        int xi[8]; float xw[8];
        taps_s4(ox, xi, xw);
        float acc = 0.0f;
        #pragma unroll
        for (int k = 0; k < 8; k++) acc += xw[k] * v[oyl * 256 + xi[k]];
        outp[(size_t)(oy0 + oyl) * G + ox] = acc;
    }
}

extern "C" void kernel_launch(void* const* d_in, const int* in_sizes, int n_in,
                              void* d_out, int out_size, void* d_ws, size_t ws_size,
                              hipStream_t stream) {
    const float* img0 = (const float*)d_in[0];
    const float* img2 = (const float*)d_in[1];
    const float* img4 = (const float*)d_in[2];
    const float* loc  = (const float*)d_in[3];
    float* out = (float*)d_out;

    glimpse_kernel<<<dim3(768), dim3(256), 0, stream>>>(img0, img2, img4, loc, out);
}